// Round 1
// baseline (502.038 us; speedup 1.0000x reference)
//
#include <hip/hip_runtime.h>
#include <hip/hip_bf16.h>

// BatchedSemiAttention: B=2, N=50000, E=800000, INP=128, KEY=64, VAL=128
#define NB    2
#define NNODE 50000
#define NEDGE 800000
#define INPD  128
#define KEYD  64
#define VALD  128
#define MTOT  (NB * NNODE)   // 100000 flattened (b,n) rows

typedef __attribute__((ext_vector_type(8))) short bf16x8;
typedef __attribute__((ext_vector_type(4))) float f32x4;

__device__ __forceinline__ unsigned short f2bf(float f) {
    unsigned u = __float_as_uint(f);
    u += 0x7FFFu + ((u >> 16) & 1u);   // RNE
    return (unsigned short)(u >> 16);
}

// ---------------------------------------------------------------------------
// Prep: kwsum[i] = sum_j k_w[i][j]; kwsum[128] = sum k_b; bf16 transposes of
// v_w and out_w into [n][k] layout so MFMA B-fragments are contiguous 16B loads.
// ---------------------------------------------------------------------------
__global__ void prep_kernel(const float* __restrict__ kw, const float* __restrict__ kb,
                            const float* __restrict__ vw, const float* __restrict__ ow,
                            float* __restrict__ kwsum,
                            unsigned short* __restrict__ vwT, unsigned short* __restrict__ owT) {
    int bid = blockIdx.x, tid = threadIdx.x;
    if (bid < 64) {
        int idx = bid * 256 + tid;            // [0,16384)
        int n = idx >> 7, k = idx & 127;
        vwT[idx] = f2bf(vw[k * VALD + n]);
    } else if (bid < 128) {
        int idx = (bid - 64) * 256 + tid;
        int n = idx >> 7, k = idx & 127;
        owT[idx] = f2bf(ow[k * VALD + n]);
    } else {
        if (tid < INPD) {
            float s = 0.f;
            for (int j = 0; j < KEYD; ++j) s += kw[tid * KEYD + j];
            kwsum[tid] = s;
        }
        if (tid == 0) {
            float s = 0.f;
            for (int j = 0; j < KEYD; ++j) s += kb[j];
            kwsum[INPD] = s;                  // kbsum
        }
    }
}

// ---------------------------------------------------------------------------
// Fused: values = x @ v_w + v_b (bf16 MFMA, stored bf16) and ksum = x·kwsum + kbsum
// (fp32, exact path feeding the softmax). Block = 512 thr = 8 waves; 16 rows/block;
// each wave owns one 16-wide n-tile. MFMA 16x16x32 bf16:
//   A[m=lane&15][k=quad*8+j], B[n=lane&15][k=quad*8+j], D[row=quad*4+r][col=lane&15]
// ---------------------------------------------------------------------------
__global__ __launch_bounds__(512)
void values_ksum_kernel(const float* __restrict__ x, const float* __restrict__ vb,
                        const float* __restrict__ kwsum,
                        const unsigned short* __restrict__ vwT,
                        unsigned short* __restrict__ values_bf, float* __restrict__ ksum) {
    int row0 = blockIdx.x * 16;
    int tid = threadIdx.x;
    int wave = tid >> 6, lane = tid & 63;
    int m = lane & 15, quad = lane >> 4;
    int n0 = wave * 16;
    f32x4 acc = {0.f, 0.f, 0.f, 0.f};
    float kpart = 0.f;
    const float* xrow = x + (size_t)(row0 + m) * INPD;
#pragma unroll
    for (int kk = 0; kk < 4; ++kk) {
        int k0 = kk * 32 + quad * 8;
        float4 xa = *(const float4*)(xrow + k0);
        float4 xb = *(const float4*)(xrow + k0 + 4);
        union { bf16x8 v; unsigned short h[8]; } ua;
        ua.h[0] = f2bf(xa.x); ua.h[1] = f2bf(xa.y); ua.h[2] = f2bf(xa.z); ua.h[3] = f2bf(xa.w);
        ua.h[4] = f2bf(xb.x); ua.h[5] = f2bf(xb.y); ua.h[6] = f2bf(xb.z); ua.h[7] = f2bf(xb.w);
        bf16x8 bfrag = *(const bf16x8*)(vwT + (size_t)(n0 + m) * INPD + k0);
        acc = __builtin_amdgcn_mfma_f32_16x16x32_bf16(ua.v, bfrag, acc, 0, 0, 0);
        if (wave == 0) {
            float4 ka = *(const float4*)(kwsum + k0);
            float4 kc = *(const float4*)(kwsum + k0 + 4);
            kpart += xa.x * ka.x + xa.y * ka.y + xa.z * ka.z + xa.w * ka.w
                   + xb.x * kc.x + xb.y * kc.y + xb.z * kc.z + xb.w * kc.w;
        }
    }
    int col = n0 + m;
    float vbc = vb[col];
#pragma unroll
    for (int r = 0; r < 4; ++r) {
        int row = quad * 4 + r;
        values_bf[(size_t)(row0 + row) * VALD + col] = f2bf(acc[r] + vbc);
    }
    if (wave == 0) {
        kpart += __shfl_xor(kpart, 16);
        kpart += __shfl_xor(kpart, 32);
        if (quad == 0) ksum[row0 + m] = kpart + kwsum[INPD];
    }
}

// ---------------------------------------------------------------------------
// CSR build
// ---------------------------------------------------------------------------
__global__ void hist_kernel(const int* __restrict__ rows, int* __restrict__ counts) {
    int e = blockIdx.x * 256 + threadIdx.x;
    if (e < NEDGE) atomicAdd(&counts[rows[e]], 1);
}

__global__ __launch_bounds__(1024)
void scan_kernel(const int* __restrict__ counts, int* __restrict__ offsets) {
    __shared__ int sums[1024];
    int t = threadIdx.x;
    const int per = (NNODE + 1023) / 1024;   // 49
    int base = t * per;
    int s = 0;
    for (int j = 0; j < per; ++j) {
        int idx = base + j;
        if (idx < NNODE) s += counts[idx];
    }
    sums[t] = s;
    __syncthreads();
    for (int off = 1; off < 1024; off <<= 1) {
        int v = (t >= off) ? sums[t - off] : 0;
        __syncthreads();
        sums[t] += v;
        __syncthreads();
    }
    int run = (t == 0) ? 0 : sums[t - 1];
    for (int j = 0; j < per; ++j) {
        int idx = base + j;
        if (idx < NNODE) { offsets[idx] = run; run += counts[idx]; }
    }
    if (t == 1023) offsets[NNODE] = run;
}

__global__ void scatter_kernel(const int* __restrict__ rows, const int* __restrict__ cols,
                               const float* __restrict__ conn,
                               const int* __restrict__ offsets, int* __restrict__ cursor,
                               int* __restrict__ col_s, float* __restrict__ conn_s) {
    int e = blockIdx.x * 256 + threadIdx.x;
    if (e < NEDGE) {
        int r = rows[e];
        int p = atomicAdd(&cursor[r], 1);
        int o = offsets[r] + p;
        col_s[o] = cols[e];
        conn_s[o] = conn[e];
    }
}

// ---------------------------------------------------------------------------
// Per-receiver-row softmax + weighted aggregation. One wave per row, both
// batches. No max-subtraction (|score| <= ~40, fp32 exp safe). Each agg row
// written exactly once -> no atomics. Lanes cover VAL=128 as 64 x bf16x2.
// ---------------------------------------------------------------------------
__global__ __launch_bounds__(256)
void aggregate_kernel(const int* __restrict__ offsets,
                      const int* __restrict__ col_s, const float* __restrict__ conn_s,
                      const float* __restrict__ ksum,
                      const unsigned short* __restrict__ values_bf,
                      unsigned short* __restrict__ agg_bf) {
    int wave = threadIdx.x >> 6, lane = threadIdx.x & 63;
    int i = blockIdx.x * 4 + wave;
    if (i >= NNODE) return;
    int start = offsets[i], end = offsets[i + 1];
    int len = end - start;
    float acc00 = 0.f, acc01 = 0.f, acc10 = 0.f, acc11 = 0.f;
    if (len > 0) {
        if (len <= 64) {
            float ex0 = 0.f, ex1 = 0.f; int colv = 0;
            if (lane < len) {
                int idx = start + lane;
                colv = col_s[idx];
                float cv = conn_s[idx];
                ex0 = __expf(cv * ksum[colv]);
                ex1 = __expf(cv * ksum[NNODE + colv]);
            }
            float s0 = ex0, s1 = ex1;
#pragma unroll
            for (int o = 1; o < 64; o <<= 1) { s0 += __shfl_xor(s0, o); s1 += __shfl_xor(s1, o); }
            float inv0 = 1.0f / s0, inv1 = 1.0f / s1;
            for (int p = 0; p < len; ++p) {
                int c = __shfl(colv, p);
                float w0 = __shfl(ex0, p) * inv0;
                float w1 = __shfl(ex1, p) * inv1;
                unsigned u0 = ((const unsigned*)(values_bf + (size_t)c * VALD))[lane];
                unsigned u1 = ((const unsigned*)(values_bf + (size_t)(NNODE + c) * VALD))[lane];
                acc00 += w0 * __uint_as_float(u0 << 16);
                acc01 += w0 * __uint_as_float(u0 & 0xFFFF0000u);
                acc10 += w1 * __uint_as_float(u1 << 16);
                acc11 += w1 * __uint_as_float(u1 & 0xFFFF0000u);
            }
        } else {
            float s0 = 0.f, s1 = 0.f;
            for (int basep = 0; basep < len; basep += 64) {
                int q = basep + lane;
                if (q < len) {
                    int idx = start + q;
                    int c = col_s[idx];
                    float cv = conn_s[idx];
                    s0 += __expf(cv * ksum[c]);
                    s1 += __expf(cv * ksum[NNODE + c]);
                }
            }
#pragma unroll
            for (int o = 1; o < 64; o <<= 1) { s0 += __shfl_xor(s0, o); s1 += __shfl_xor(s1, o); }
            float inv0 = 1.0f / s0, inv1 = 1.0f / s1;
            for (int p = 0; p < len; ++p) {
                int idx = start + p;
                int c = col_s[idx];
                float cv = conn_s[idx];
                float w0 = __expf(cv * ksum[c]) * inv0;
                float w1 = __expf(cv * ksum[NNODE + c]) * inv1;
                unsigned u0 = ((const unsigned*)(values_bf + (size_t)c * VALD))[lane];
                unsigned u1 = ((const unsigned*)(values_bf + (size_t)(NNODE + c) * VALD))[lane];
                acc00 += w0 * __uint_as_float(u0 << 16);
                acc01 += w0 * __uint_as_float(u0 & 0xFFFF0000u);
                acc10 += w1 * __uint_as_float(u1 << 16);
                acc11 += w1 * __uint_as_float(u1 & 0xFFFF0000u);
            }
        }
    }
    unsigned o0 = ((unsigned)f2bf(acc01) << 16) | (unsigned)f2bf(acc00);
    unsigned o1 = ((unsigned)f2bf(acc11) << 16) | (unsigned)f2bf(acc10);
    ((unsigned*)(agg_bf + (size_t)i * VALD))[lane] = o0;
    ((unsigned*)(agg_bf + (size_t)(NNODE + i) * VALD))[lane] = o1;
}

// ---------------------------------------------------------------------------
// out = LN(silu(agg @ out_w + out_b)) * g + b. Block = 256 thr = 4 waves,
// 16 rows x 128 cols per block (each wave two 16-wide n-tiles) so the
// LayerNorm over the 128-dim is block-local via LDS.
// ---------------------------------------------------------------------------
__global__ __launch_bounds__(256)
void out_kernel(const unsigned short* __restrict__ agg_bf,
                const unsigned short* __restrict__ owT,
                const float* __restrict__ ob,
                const float* __restrict__ lng, const float* __restrict__ lnb,
                float* __restrict__ out) {
    __shared__ float hs[16][VALD + 2];
    __shared__ float ps[16][16];
    __shared__ float psq[16][16];
    __shared__ float mu_s[16], rs_s[16];
    int m0 = blockIdx.x * 16;
    int tid = threadIdx.x;
    int wave = tid >> 6, lane = tid & 63;
    int m = lane & 15, quad = lane >> 4;
    int n0 = wave * 32;
    f32x4 a0 = {0.f, 0.f, 0.f, 0.f}, a1 = {0.f, 0.f, 0.f, 0.f};
    const unsigned short* arow = agg_bf + (size_t)(m0 + m) * VALD;
#pragma unroll
    for (int kk = 0; kk < 4; ++kk) {
        int k0 = kk * 32 + quad * 8;
        bf16x8 af = *(const bf16x8*)(arow + k0);
        bf16x8 b0 = *(const bf16x8*)(owT + (size_t)(n0 + m) * VALD + k0);
        bf16x8 b1 = *(const bf16x8*)(owT + (size_t)(n0 + 16 + m) * VALD + k0);
        a0 = __builtin_amdgcn_mfma_f32_16x16x32_bf16(af, b0, a0, 0, 0, 0);
        a1 = __builtin_amdgcn_mfma_f32_16x16x32_bf16(af, b1, a1, 0, 0, 0);
    }
#pragma unroll
    for (int r = 0; r < 4; ++r) {
        int row = quad * 4 + r;
        {
            int col = n0 + m;
            float h = a0[r] + ob[col];
            hs[row][col] = h / (1.f + __expf(-h));
        }
        {
            int col = n0 + 16 + m;
            float h = a1[r] + ob[col];
            hs[row][col] = h / (1.f + __expf(-h));
        }
    }
    __syncthreads();
    {
        int row = tid >> 4, seg = tid & 15;
        float s = 0.f, q = 0.f;
#pragma unroll
        for (int j = 0; j < 8; ++j) {
            float v = hs[row][seg * 8 + j];
            s += v; q += v * v;
        }
        ps[row][seg] = s; psq[row][seg] = q;
    }
    __syncthreads();
    if (tid < 16) {
        float s = 0.f, q = 0.f;
#pragma unroll
        for (int j = 0; j < 16; ++j) { s += ps[tid][j]; q += psq[tid][j]; }
        float mu = s * (1.f / 128.f);
        float var = q * (1.f / 128.f) - mu * mu;
        mu_s[tid] = mu;
        rs_s[tid] = rsqrtf(var + 1e-5f);
    }
    __syncthreads();
#pragma unroll
    for (int j = 0; j < 8; ++j) {
        int e = tid + 256 * j;
        int row = e >> 7, col = e & 127;
        out[(size_t)(m0 + row) * VALD + col] =
            (hs[row][col] - mu_s[row]) * rs_s[row] * lng[col] + lnb[col];
    }
}

// ---------------------------------------------------------------------------
extern "C" void kernel_launch(void* const* d_in, const int* in_sizes, int n_in,
                              void* d_out, int out_size, void* d_ws, size_t ws_size,
                              hipStream_t stream) {
    (void)in_sizes; (void)n_in; (void)out_size; (void)ws_size;
    const float* x    = (const float*)d_in[0];
    const float* conn = (const float*)d_in[1];
    const float* kw   = (const float*)d_in[2];
    const float* kb   = (const float*)d_in[3];
    const float* vw   = (const float*)d_in[4];
    const float* vb   = (const float*)d_in[5];
    const float* ow   = (const float*)d_in[6];
    const float* ob   = (const float*)d_in[7];
    const float* lng  = (const float*)d_in[8];
    const float* lnb  = (const float*)d_in[9];
    const int* rows   = (const int*)d_in[10];
    const int* cols   = (const int*)d_in[11];
    float* out        = (float*)d_out;

    char* w = (char*)d_ws;
    auto alloc = [&](size_t bytes) {
        char* p = w;
        w += (bytes + 255) & ~(size_t)255;
        return p;
    };
    unsigned short* values_bf = (unsigned short*)alloc((size_t)MTOT * VALD * 2);
    unsigned short* agg_bf    = (unsigned short*)alloc((size_t)MTOT * VALD * 2);
    float* ksum   = (float*)alloc((size_t)MTOT * 4);
    float* kwsum  = (float*)alloc(256 * 4);
    int*   counts = (int*)alloc((size_t)NNODE * 4 * 2);  // counts + cursor contiguous
    int*   cursor = counts + NNODE;
    int*   offsets = (int*)alloc((size_t)(NNODE + 1) * 4);
    int*   col_s  = (int*)alloc((size_t)NEDGE * 4);
    float* conn_s = (float*)alloc((size_t)NEDGE * 4);
    unsigned short* vwT = (unsigned short*)alloc((size_t)INPD * VALD * 2);
    unsigned short* owT = (unsigned short*)alloc((size_t)VALD * VALD * 2);

    hipMemsetAsync(counts, 0, (size_t)NNODE * 4 * 2, stream);
    prep_kernel<<<129, 256, 0, stream>>>(kw, kb, vw, ow, kwsum, vwT, owT);
    values_ksum_kernel<<<MTOT / 16, 512, 0, stream>>>(x, vb, kwsum, vwT, values_bf, ksum);
    hist_kernel<<<(NEDGE + 255) / 256, 256, 0, stream>>>(rows, counts);
    scan_kernel<<<1, 1024, 0, stream>>>(counts, offsets);
    scatter_kernel<<<(NEDGE + 255) / 256, 256, 0, stream>>>(rows, cols, conn, offsets, cursor, col_s, conn_s);
    aggregate_kernel<<<(NNODE + 3) / 4, 256, 0, stream>>>(offsets, col_s, conn_s, ksum, values_bf, agg_bf);
    out_kernel<<<MTOT / 16, 256, 0, stream>>>(agg_bf, owT, ob, lng, lnb, out);
}

// Round 2
// 462.613 us; speedup vs baseline: 1.0852x; 1.0852x over previous
//
#include <hip/hip_runtime.h>
#include <hip/hip_bf16.h>

// BatchedSemiAttention: B=2, N=50000, E=800000, INP=128, KEY=64, VAL=128
#define NB    2
#define NNODE 50000
#define NEDGE 800000
#define INPD  128
#define KEYD  64
#define VALD  128
#define MTOT  (NB * NNODE)   // 100000 flattened (b,n) rows
#define VBLK  3125           // NNODE/16 blocks for the values GEMM part

typedef __attribute__((ext_vector_type(8))) short bf16x8;
typedef __attribute__((ext_vector_type(4))) float f32x4;

__device__ __forceinline__ unsigned short f2bf(float f) {
    unsigned u = __float_as_uint(f);
    u += 0x7FFFu + ((u >> 16) & 1u);   // RNE
    return (unsigned short)(u >> 16);
}

// ---------------------------------------------------------------------------
// Prep: bf16 transposes of v_w / out_w into [n][k]; kwsum (col-sums of k_w,
// +kb sum at [128]); zero the CSR counts. All fused: one launch.
// ---------------------------------------------------------------------------
__global__ void prep_kernel(const float* __restrict__ kw, const float* __restrict__ kb,
                            const float* __restrict__ vw, const float* __restrict__ ow,
                            float* __restrict__ kwsum,
                            unsigned short* __restrict__ vwT, unsigned short* __restrict__ owT,
                            int* __restrict__ counts) {
    int bid = blockIdx.x, tid = threadIdx.x;
    if (bid < 64) {
        int idx = bid * 256 + tid;            // [0,16384)
        int n = idx >> 7, k = idx & 127;
        vwT[idx] = f2bf(vw[k * VALD + n]);
    } else if (bid < 128) {
        int idx = (bid - 64) * 256 + tid;
        int n = idx >> 7, k = idx & 127;
        owT[idx] = f2bf(ow[k * VALD + n]);
    } else if (bid == 128) {
        if (tid < INPD) {
            float s = 0.f;
            for (int j = 0; j < KEYD; ++j) s += kw[tid * KEYD + j];
            kwsum[tid] = s;
        }
        if (tid == 0) {
            float s = 0.f;
            for (int j = 0; j < KEYD; ++j) s += kb[j];
            kwsum[INPD] = s;                  // kbsum
        }
    } else {
        int idx = (bid - 129) * 256 + tid;
        if (idx < NNODE) counts[idx] = 0;
    }
}

// ---------------------------------------------------------------------------
// Fused: values GEMM for BOTH batches of 16 nodes per block (so the packed
// batch-interleaved store is local), ksum, and the edge histogram (extra
// blocks). values_pk layout per node: 64 x uint2 { b0 cols(2l,2l+1) bf16x2,
// b1 cols(2l,2l+1) bf16x2 }  -> one dwordx2 per edge in aggregate.
// ---------------------------------------------------------------------------
__global__ __launch_bounds__(512)
void values_build_kernel(const float* __restrict__ x, const float* __restrict__ vb,
                         const float* __restrict__ kwsum,
                         const unsigned short* __restrict__ vwT,
                         const int* __restrict__ rows_e,
                         uint2* __restrict__ values_pk, float* __restrict__ ksum,
                         int* __restrict__ counts) {
    if (blockIdx.x >= VBLK) {
        // histogram part, overlapped with the GEMM blocks
        int e = (blockIdx.x - VBLK) * 512 + threadIdx.x;
        if (e < NEDGE) atomicAdd(&counts[rows_e[e]], 1);
        return;
    }
    int node0 = blockIdx.x * 16;
    int tid = threadIdx.x;
    int wave = tid >> 6, lane = tid & 63;
    int m = lane & 15, quad = lane >> 4;
    int n0 = wave * 16;
    f32x4 acc0 = {0.f, 0.f, 0.f, 0.f};   // batch 0
    f32x4 acc1 = {0.f, 0.f, 0.f, 0.f};   // batch 1
    float kpart = 0.f;
    const float* xr0 = x + (size_t)(node0 + m) * INPD;
    const float* xr1 = x + (size_t)(NNODE + node0 + m) * INPD;
#pragma unroll
    for (int kk = 0; kk < 4; ++kk) {
        int k0 = kk * 32 + quad * 8;
        float4 a0 = *(const float4*)(xr0 + k0);
        float4 a1 = *(const float4*)(xr0 + k0 + 4);
        float4 c0 = *(const float4*)(xr1 + k0);
        float4 c1 = *(const float4*)(xr1 + k0 + 4);
        bf16x8 bfrag = *(const bf16x8*)(vwT + (size_t)(n0 + m) * INPD + k0);
        union { bf16x8 v; unsigned short h[8]; } ua;
        ua.h[0] = f2bf(a0.x); ua.h[1] = f2bf(a0.y); ua.h[2] = f2bf(a0.z); ua.h[3] = f2bf(a0.w);
        ua.h[4] = f2bf(a1.x); ua.h[5] = f2bf(a1.y); ua.h[6] = f2bf(a1.z); ua.h[7] = f2bf(a1.w);
        acc0 = __builtin_amdgcn_mfma_f32_16x16x32_bf16(ua.v, bfrag, acc0, 0, 0, 0);
        union { bf16x8 v; unsigned short h[8]; } ub;
        ub.h[0] = f2bf(c0.x); ub.h[1] = f2bf(c0.y); ub.h[2] = f2bf(c0.z); ub.h[3] = f2bf(c0.w);
        ub.h[4] = f2bf(c1.x); ub.h[5] = f2bf(c1.y); ub.h[6] = f2bf(c1.z); ub.h[7] = f2bf(c1.w);
        acc1 = __builtin_amdgcn_mfma_f32_16x16x32_bf16(ub.v, bfrag, acc1, 0, 0, 0);
        if (wave == 0) {
            float4 ka = *(const float4*)(kwsum + k0);
            float4 kc = *(const float4*)(kwsum + k0 + 4);
            kpart += a0.x * ka.x + a0.y * ka.y + a0.z * ka.z + a0.w * ka.w
                   + a1.x * kc.x + a1.y * kc.y + a1.z * kc.z + a1.w * kc.w;
        } else if (wave == 1) {
            float4 ka = *(const float4*)(kwsum + k0);
            float4 kc = *(const float4*)(kwsum + k0 + 4);
            kpart += c0.x * ka.x + c0.y * ka.y + c0.z * ka.z + c0.w * ka.w
                   + c1.x * kc.x + c1.y * kc.y + c1.z * kc.z + c1.w * kc.w;
        }
    }
    int col = n0 + m;
    float vbc = vb[col];
    size_t pairoff = (size_t)(col >> 1) * 8 + (size_t)(col & 1) * 2;
    char* basep = (char*)values_pk;
#pragma unroll
    for (int r = 0; r < 4; ++r) {
        int node = node0 + quad * 4 + r;
        char* p = basep + (size_t)node * 512 + pairoff;
        *(unsigned short*)p       = f2bf(acc0[r] + vbc);   // batch 0 at +0
        *(unsigned short*)(p + 4) = f2bf(acc1[r] + vbc);   // batch 1 at +4
    }
    if (wave < 2) {
        kpart += __shfl_xor(kpart, 16);
        kpart += __shfl_xor(kpart, 32);
        if (quad == 0) ksum[(wave == 0 ? 0 : NNODE) + node0 + m] = kpart + kwsum[INPD];
    }
}

// ---------------------------------------------------------------------------
// Single-block scan of counts -> offsets, and cursor = offsets (scatter uses
// cursor directly as the running write position).
// ---------------------------------------------------------------------------
__global__ __launch_bounds__(1024)
void scan_kernel(const int* __restrict__ counts, int* __restrict__ offsets,
                 int* __restrict__ cursor) {
    __shared__ int sums[1024];
    int t = threadIdx.x;
    const int per = (NNODE + 1023) / 1024;   // 49
    int base = t * per;
    int s = 0;
    for (int j = 0; j < per; ++j) {
        int idx = base + j;
        if (idx < NNODE) s += counts[idx];
    }
    sums[t] = s;
    __syncthreads();
    for (int off = 1; off < 1024; off <<= 1) {
        int v = (t >= off) ? sums[t - off] : 0;
        __syncthreads();
        sums[t] += v;
        __syncthreads();
    }
    int run = (t == 0) ? 0 : sums[t - 1];
    for (int j = 0; j < per; ++j) {
        int idx = base + j;
        if (idx < NNODE) { offsets[idx] = run; cursor[idx] = run; run += counts[idx]; }
    }
    if (t == 1023) offsets[NNODE] = run;
}

__global__ void scatter_kernel(const int* __restrict__ rows, const int* __restrict__ cols,
                               const float* __restrict__ conn,
                               int* __restrict__ cursor, uint2* __restrict__ edge_s) {
    int e = blockIdx.x * 256 + threadIdx.x;
    if (e < NEDGE) {
        int r = rows[e];
        int o = atomicAdd(&cursor[r], 1);
        edge_s[o] = make_uint2((unsigned)cols[e], __float_as_uint(conn[e]));
    }
}

// ---------------------------------------------------------------------------
// Per-receiver softmax + weighted aggregation. 2 rows per wave, p-loop
// unrolled x4 for memory-level parallelism; one dwordx2 gather per edge
// covers both batches. No max-subtraction (|score| <= ~40, fp32-safe).
// ---------------------------------------------------------------------------
__global__ __launch_bounds__(256)
void aggregate_kernel(const int* __restrict__ offsets,
                      const uint2* __restrict__ edge_s,
                      const float* __restrict__ ksum,
                      const uint2* __restrict__ values_pk,
                      unsigned short* __restrict__ agg_bf) {
    int wave = threadIdx.x >> 6, lane = threadIdx.x & 63;
    int wid = blockIdx.x * 4 + wave;
    for (int rr = 0; rr < 2; ++rr) {
        int i = wid * 2 + rr;
        if (i >= NNODE) break;
        int start = offsets[i], len = offsets[i + 1] - start;
        float acc00 = 0.f, acc01 = 0.f, acc10 = 0.f, acc11 = 0.f;
        if (len > 0) {
            if (len <= 64) {
                float ex0 = 0.f, ex1 = 0.f; int colv = 0;
                if (lane < len) {
                    uint2 e = edge_s[start + lane];
                    colv = (int)e.x;
                    float cv = __uint_as_float(e.y);
                    ex0 = __expf(cv * ksum[colv]);
                    ex1 = __expf(cv * ksum[NNODE + colv]);
                }
                float s0 = ex0, s1 = ex1;
#pragma unroll
                for (int o = 1; o < 64; o <<= 1) { s0 += __shfl_xor(s0, o); s1 += __shfl_xor(s1, o); }
                float inv0 = 1.0f / s0, inv1 = 1.0f / s1;
                int p = 0;
                for (; p + 3 < len; p += 4) {
                    int c0 = __shfl(colv, p),     c1 = __shfl(colv, p + 1);
                    int c2 = __shfl(colv, p + 2), c3 = __shfl(colv, p + 3);
                    float wa0 = __shfl(ex0, p) * inv0,     wb0 = __shfl(ex1, p) * inv1;
                    float wa1 = __shfl(ex0, p + 1) * inv0, wb1 = __shfl(ex1, p + 1) * inv1;
                    float wa2 = __shfl(ex0, p + 2) * inv0, wb2 = __shfl(ex1, p + 2) * inv1;
                    float wa3 = __shfl(ex0, p + 3) * inv0, wb3 = __shfl(ex1, p + 3) * inv1;
                    uint2 v0 = values_pk[(size_t)c0 * 64 + lane];
                    uint2 v1 = values_pk[(size_t)c1 * 64 + lane];
                    uint2 v2 = values_pk[(size_t)c2 * 64 + lane];
                    uint2 v3 = values_pk[(size_t)c3 * 64 + lane];
                    acc00 += wa0 * __uint_as_float(v0.x << 16) + wa1 * __uint_as_float(v1.x << 16)
                           + wa2 * __uint_as_float(v2.x << 16) + wa3 * __uint_as_float(v3.x << 16);
                    acc01 += wa0 * __uint_as_float(v0.x & 0xFFFF0000u) + wa1 * __uint_as_float(v1.x & 0xFFFF0000u)
                           + wa2 * __uint_as_float(v2.x & 0xFFFF0000u) + wa3 * __uint_as_float(v3.x & 0xFFFF0000u);
                    acc10 += wb0 * __uint_as_float(v0.y << 16) + wb1 * __uint_as_float(v1.y << 16)
                           + wb2 * __uint_as_float(v2.y << 16) + wb3 * __uint_as_float(v3.y << 16);
                    acc11 += wb0 * __uint_as_float(v0.y & 0xFFFF0000u) + wb1 * __uint_as_float(v1.y & 0xFFFF0000u)
                           + wb2 * __uint_as_float(v2.y & 0xFFFF0000u) + wb3 * __uint_as_float(v3.y & 0xFFFF0000u);
                }
                for (; p < len; ++p) {
                    int c = __shfl(colv, p);
                    float w0 = __shfl(ex0, p) * inv0;
                    float w1 = __shfl(ex1, p) * inv1;
                    uint2 v = values_pk[(size_t)c * 64 + lane];
                    acc00 += w0 * __uint_as_float(v.x << 16);
                    acc01 += w0 * __uint_as_float(v.x & 0xFFFF0000u);
                    acc10 += w1 * __uint_as_float(v.y << 16);
                    acc11 += w1 * __uint_as_float(v.y & 0xFFFF0000u);
                }
            } else {
                float s0 = 0.f, s1 = 0.f;
                for (int basep = 0; basep < len; basep += 64) {
                    int q = basep + lane;
                    if (q < len) {
                        uint2 e = edge_s[start + q];
                        int c = (int)e.x;
                        float cv = __uint_as_float(e.y);
                        s0 += __expf(cv * ksum[c]);
                        s1 += __expf(cv * ksum[NNODE + c]);
                    }
                }
#pragma unroll
                for (int o = 1; o < 64; o <<= 1) { s0 += __shfl_xor(s0, o); s1 += __shfl_xor(s1, o); }
                float inv0 = 1.0f / s0, inv1 = 1.0f / s1;
                for (int p = 0; p < len; ++p) {
                    uint2 e = edge_s[start + p];
                    int c = (int)e.x;
                    float cv = __uint_as_float(e.y);
                    float w0 = __expf(cv * ksum[c]) * inv0;
                    float w1 = __expf(cv * ksum[NNODE + c]) * inv1;
                    uint2 v = values_pk[(size_t)c * 64 + lane];
                    acc00 += w0 * __uint_as_float(v.x << 16);
                    acc01 += w0 * __uint_as_float(v.x & 0xFFFF0000u);
                    acc10 += w1 * __uint_as_float(v.y << 16);
                    acc11 += w1 * __uint_as_float(v.y & 0xFFFF0000u);
                }
            }
        }
        unsigned o0 = ((unsigned)f2bf(acc01) << 16) | (unsigned)f2bf(acc00);
        unsigned o1 = ((unsigned)f2bf(acc11) << 16) | (unsigned)f2bf(acc10);
        ((unsigned*)(agg_bf + (size_t)i * VALD))[lane] = o0;
        ((unsigned*)(agg_bf + (size_t)(NNODE + i) * VALD))[lane] = o1;
    }
}

// ---------------------------------------------------------------------------
// out = LN(silu(agg @ out_w + out_b)) * g + b. 16 rows x 128 cols per block.
// ---------------------------------------------------------------------------
__global__ __launch_bounds__(256)
void out_kernel(const unsigned short* __restrict__ agg_bf,
                const unsigned short* __restrict__ owT,
                const float* __restrict__ ob,
                const float* __restrict__ lng, const float* __restrict__ lnb,
                float* __restrict__ out) {
    __shared__ float hs[16][VALD + 2];
    __shared__ float ps[16][16];
    __shared__ float psq[16][16];
    __shared__ float mu_s[16], rs_s[16];
    int m0 = blockIdx.x * 16;
    int tid = threadIdx.x;
    int wave = tid >> 6, lane = tid & 63;
    int m = lane & 15, quad = lane >> 4;
    int n0 = wave * 32;
    f32x4 a0 = {0.f, 0.f, 0.f, 0.f}, a1 = {0.f, 0.f, 0.f, 0.f};
    const unsigned short* arow = agg_bf + (size_t)(m0 + m) * VALD;
#pragma unroll
    for (int kk = 0; kk < 4; ++kk) {
        int k0 = kk * 32 + quad * 8;
        bf16x8 af = *(const bf16x8*)(arow + k0);
        bf16x8 b0 = *(const bf16x8*)(owT + (size_t)(n0 + m) * VALD + k0);
        bf16x8 b1 = *(const bf16x8*)(owT + (size_t)(n0 + 16 + m) * VALD + k0);
        a0 = __builtin_amdgcn_mfma_f32_16x16x32_bf16(af, b0, a0, 0, 0, 0);
        a1 = __builtin_amdgcn_mfma_f32_16x16x32_bf16(af, b1, a1, 0, 0, 0);
    }
#pragma unroll
    for (int r = 0; r < 4; ++r) {
        int row = quad * 4 + r;
        {
            int col = n0 + m;
            float h = a0[r] + ob[col];
            hs[row][col] = h / (1.f + __expf(-h));
        }
        {
            int col = n0 + 16 + m;
            float h = a1[r] + ob[col];
            hs[row][col] = h / (1.f + __expf(-h));
        }
    }
    __syncthreads();
    {
        int row = tid >> 4, seg = tid & 15;
        float s = 0.f, q = 0.f;
#pragma unroll
        for (int j = 0; j < 8; ++j) {
            float v = hs[row][seg * 8 + j];
            s += v; q += v * v;
        }
        ps[row][seg] = s; psq[row][seg] = q;
    }
    __syncthreads();
    if (tid < 16) {
        float s = 0.f, q = 0.f;
#pragma unroll
        for (int j = 0; j < 16; ++j) { s += ps[tid][j]; q += psq[tid][j]; }
        float mu = s * (1.f / 128.f);
        float var = q * (1.f / 128.f) - mu * mu;
        mu_s[tid] = mu;
        rs_s[tid] = rsqrtf(var + 1e-5f);
    }
    __syncthreads();
#pragma unroll
    for (int j = 0; j < 8; ++j) {
        int e = tid + 256 * j;
        int row = e >> 7, col = e & 127;
        out[(size_t)(m0 + row) * VALD + col] =
            (hs[row][col] - mu_s[row]) * rs_s[row] * lng[col] + lnb[col];
    }
}

// ---------------------------------------------------------------------------
extern "C" void kernel_launch(void* const* d_in, const int* in_sizes, int n_in,
                              void* d_out, int out_size, void* d_ws, size_t ws_size,
                              hipStream_t stream) {
    (void)in_sizes; (void)n_in; (void)out_size; (void)ws_size;
    const float* x    = (const float*)d_in[0];
    const float* conn = (const float*)d_in[1];
    const float* kw   = (const float*)d_in[2];
    const float* kb   = (const float*)d_in[3];
    const float* vw   = (const float*)d_in[4];
    const float* vb   = (const float*)d_in[5];
    const float* ow   = (const float*)d_in[6];
    const float* ob   = (const float*)d_in[7];
    const float* lng  = (const float*)d_in[8];
    const float* lnb  = (const float*)d_in[9];
    const int* rows   = (const int*)d_in[10];
    const int* cols   = (const int*)d_in[11];
    float* out        = (float*)d_out;

    char* w = (char*)d_ws;
    auto alloc = [&](size_t bytes) {
        char* p = w;
        w += (bytes + 255) & ~(size_t)255;
        return p;
    };
    uint2* values_pk       = (uint2*)alloc((size_t)NNODE * 512);          // 25.6 MB
    unsigned short* agg_bf = (unsigned short*)alloc((size_t)MTOT * VALD * 2); // 25.6 MB
    float* ksum   = (float*)alloc((size_t)MTOT * 4);
    float* kwsum  = (float*)alloc(256 * 4);
    int*   counts = (int*)alloc((size_t)NNODE * 4);
    int*   cursor = (int*)alloc((size_t)NNODE * 4);
    int*   offsets = (int*)alloc((size_t)(NNODE + 1) * 4);
    uint2* edge_s = (uint2*)alloc((size_t)NEDGE * 8);                     // 6.4 MB
    unsigned short* vwT = (unsigned short*)alloc((size_t)INPD * VALD * 2);
    unsigned short* owT = (unsigned short*)alloc((size_t)VALD * VALD * 2);

    prep_kernel<<<129 + 196, 256, 0, stream>>>(kw, kb, vw, ow, kwsum, vwT, owT, counts);
    values_build_kernel<<<VBLK + (NEDGE + 511) / 512, 512, 0, stream>>>(
        x, vb, kwsum, vwT, rows, values_pk, ksum, counts);
    scan_kernel<<<1, 1024, 0, stream>>>(counts, offsets, cursor);
    scatter_kernel<<<(NEDGE + 255) / 256, 256, 0, stream>>>(rows, cols, conn, cursor, edge_s);
    aggregate_kernel<<<(NNODE + 7) / 8, 256, 0, stream>>>(offsets, edge_s, ksum, values_pk, agg_bf);
    out_kernel<<<MTOT / 16, 256, 0, stream>>>(agg_bf, owT, ob, lng, lnb, out);
}

// Round 3
// 348.688 us; speedup vs baseline: 1.4398x; 1.3267x over previous
//
#include <hip/hip_runtime.h>
#include <hip/hip_bf16.h>

// BatchedSemiAttention: B=2, N=50000, E=800000, INP=128, KEY=64, VAL=128
#define NB    2
#define NNODE 50000
#define NEDGE 800000
#define INPD  128
#define KEYD  64
#define VALD  128
#define MTOT  (NB * NNODE)   // 100000 flattened (b,n) rows
#define VBLK  3125           // NNODE/16 blocks for the values GEMM part
#define CHUNK 512
#define NCHUNK ((NNODE + CHUNK - 1) / CHUNK)   // 98

typedef __attribute__((ext_vector_type(8))) short bf16x8;
typedef __attribute__((ext_vector_type(4))) float f32x4;

__device__ __forceinline__ unsigned short f2bf(float f) {
    unsigned u = __float_as_uint(f);
    u += 0x7FFFu + ((u >> 16) & 1u);   // RNE
    return (unsigned short)(u >> 16);
}

// ---------------------------------------------------------------------------
// Prep: bf16 transposes of v_w / out_w into [n][k]; kwsum (col-sums of k_w,
// +kb sum at [128]); zero the CSR counts. All fused: one launch.
// ---------------------------------------------------------------------------
__global__ void prep_kernel(const float* __restrict__ kw, const float* __restrict__ kb,
                            const float* __restrict__ vw, const float* __restrict__ ow,
                            float* __restrict__ kwsum,
                            unsigned short* __restrict__ vwT, unsigned short* __restrict__ owT,
                            int* __restrict__ counts) {
    int bid = blockIdx.x, tid = threadIdx.x;
    if (bid < 64) {
        int idx = bid * 256 + tid;            // [0,16384)
        int n = idx >> 7, k = idx & 127;
        vwT[idx] = f2bf(vw[k * VALD + n]);
    } else if (bid < 128) {
        int idx = (bid - 64) * 256 + tid;
        int n = idx >> 7, k = idx & 127;
        owT[idx] = f2bf(ow[k * VALD + n]);
    } else if (bid == 128) {
        if (tid < INPD) {
            float s = 0.f;
            for (int j = 0; j < KEYD; ++j) s += kw[tid * KEYD + j];
            kwsum[tid] = s;
        }
        if (tid == 0) {
            float s = 0.f;
            for (int j = 0; j < KEYD; ++j) s += kb[j];
            kwsum[INPD] = s;                  // kbsum
        }
    } else {
        int idx = (bid - 129) * 256 + tid;
        if (idx < NNODE) counts[idx] = 0;
    }
}

// ---------------------------------------------------------------------------
// Fused: values GEMM for BOTH batches of 16 nodes per block (so the packed
// batch-interleaved store is local), ksum, and the edge histogram (extra
// blocks). values_pk layout per node: 64 x uint2 { b0 cols(2l,2l+1) bf16x2,
// b1 cols(2l,2l+1) bf16x2 }  -> one dwordx2 per edge in aggregate.
// ---------------------------------------------------------------------------
__global__ __launch_bounds__(512)
void values_build_kernel(const float* __restrict__ x, const float* __restrict__ vb,
                         const float* __restrict__ kwsum,
                         const unsigned short* __restrict__ vwT,
                         const int* __restrict__ rows_e,
                         uint2* __restrict__ values_pk, float* __restrict__ ksum,
                         int* __restrict__ counts) {
    if (blockIdx.x >= VBLK) {
        // histogram part, overlapped with the GEMM blocks
        int e = (blockIdx.x - VBLK) * 512 + threadIdx.x;
        if (e < NEDGE) atomicAdd(&counts[rows_e[e]], 1);
        return;
    }
    int node0 = blockIdx.x * 16;
    int tid = threadIdx.x;
    int wave = tid >> 6, lane = tid & 63;
    int m = lane & 15, quad = lane >> 4;
    int n0 = wave * 16;
    f32x4 acc0 = {0.f, 0.f, 0.f, 0.f};   // batch 0
    f32x4 acc1 = {0.f, 0.f, 0.f, 0.f};   // batch 1
    float kpart = 0.f;
    const float* xr0 = x + (size_t)(node0 + m) * INPD;
    const float* xr1 = x + (size_t)(NNODE + node0 + m) * INPD;
#pragma unroll
    for (int kk = 0; kk < 4; ++kk) {
        int k0 = kk * 32 + quad * 8;
        float4 a0 = *(const float4*)(xr0 + k0);
        float4 a1 = *(const float4*)(xr0 + k0 + 4);
        float4 c0 = *(const float4*)(xr1 + k0);
        float4 c1 = *(const float4*)(xr1 + k0 + 4);
        bf16x8 bfrag = *(const bf16x8*)(vwT + (size_t)(n0 + m) * INPD + k0);
        union { bf16x8 v; unsigned short h[8]; } ua;
        ua.h[0] = f2bf(a0.x); ua.h[1] = f2bf(a0.y); ua.h[2] = f2bf(a0.z); ua.h[3] = f2bf(a0.w);
        ua.h[4] = f2bf(a1.x); ua.h[5] = f2bf(a1.y); ua.h[6] = f2bf(a1.z); ua.h[7] = f2bf(a1.w);
        acc0 = __builtin_amdgcn_mfma_f32_16x16x32_bf16(ua.v, bfrag, acc0, 0, 0, 0);
        union { bf16x8 v; unsigned short h[8]; } ub;
        ub.h[0] = f2bf(c0.x); ub.h[1] = f2bf(c0.y); ub.h[2] = f2bf(c0.z); ub.h[3] = f2bf(c0.w);
        ub.h[4] = f2bf(c1.x); ub.h[5] = f2bf(c1.y); ub.h[6] = f2bf(c1.z); ub.h[7] = f2bf(c1.w);
        acc1 = __builtin_amdgcn_mfma_f32_16x16x32_bf16(ub.v, bfrag, acc1, 0, 0, 0);
        if (wave == 0) {
            float4 ka = *(const float4*)(kwsum + k0);
            float4 kc = *(const float4*)(kwsum + k0 + 4);
            kpart += a0.x * ka.x + a0.y * ka.y + a0.z * ka.z + a0.w * ka.w
                   + a1.x * kc.x + a1.y * kc.y + a1.z * kc.z + a1.w * kc.w;
        } else if (wave == 1) {
            float4 ka = *(const float4*)(kwsum + k0);
            float4 kc = *(const float4*)(kwsum + k0 + 4);
            kpart += c0.x * ka.x + c0.y * ka.y + c0.z * ka.z + c0.w * ka.w
                   + c1.x * kc.x + c1.y * kc.y + c1.z * kc.z + c1.w * kc.w;
        }
    }
    int col = n0 + m;
    float vbc = vb[col];
    size_t pairoff = (size_t)(col >> 1) * 8 + (size_t)(col & 1) * 2;
    char* basep = (char*)values_pk;
#pragma unroll
    for (int r = 0; r < 4; ++r) {
        int node = node0 + quad * 4 + r;
        char* p = basep + (size_t)node * 512 + pairoff;
        *(unsigned short*)p       = f2bf(acc0[r] + vbc);   // batch 0 at +0
        *(unsigned short*)(p + 4) = f2bf(acc1[r] + vbc);   // batch 1 at +4
    }
    if (wave < 2) {
        kpart += __shfl_xor(kpart, 16);
        kpart += __shfl_xor(kpart, 32);
        if (quad == 0) ksum[(wave == 0 ? 0 : NNODE) + node0 + m] = kpart + kwsum[INPD];
    }
}

// ---------------------------------------------------------------------------
// Device-wide exclusive scan of counts -> offsets (+cursor copy), 3 phases.
// Phase 1: per-chunk (512 elems) sums. Phase 2: scan the 98 chunk sums.
// Phase 3: block-local scan + chunk base, coalesced writes.
// ---------------------------------------------------------------------------
__global__ __launch_bounds__(256)
void scan1_kernel(const int* __restrict__ counts, int* __restrict__ psum) {
    __shared__ int wsum[4];
    int b = blockIdx.x, t = threadIdx.x;
    int i0 = b * CHUNK + t, i1 = i0 + 256;
    int v = 0;
    if (i0 < NNODE) v += counts[i0];
    if (i1 < NNODE) v += counts[i1];
#pragma unroll
    for (int o = 1; o < 64; o <<= 1) v += __shfl_xor(v, o);
    int lane = t & 63, wv = t >> 6;
    if (lane == 0) wsum[wv] = v;
    __syncthreads();
    if (t == 0) psum[b] = wsum[0] + wsum[1] + wsum[2] + wsum[3];
}

__global__ __launch_bounds__(128)
void scan2_kernel(const int* __restrict__ psum, int* __restrict__ pbase,
                  int* __restrict__ offsets) {
    __shared__ int s[128];
    int t = threadIdx.x;
    int v = (t < NCHUNK) ? psum[t] : 0;
    s[t] = v;
    __syncthreads();
    for (int o = 1; o < 128; o <<= 1) {
        int y = (t >= o) ? s[t - o] : 0;
        __syncthreads();
        s[t] += y;
        __syncthreads();
    }
    if (t < NCHUNK) pbase[t] = s[t] - v;          // exclusive chunk base
    if (t == NCHUNK - 1) offsets[NNODE] = s[t];   // total edge count
}

__global__ __launch_bounds__(256)
void scan3_kernel(const int* __restrict__ counts, const int* __restrict__ pbase,
                  int* __restrict__ offsets, int* __restrict__ cursor) {
    __shared__ int wt0[4], wt1[4];
    int b = blockIdx.x, t = threadIdx.x;
    int lane = t & 63, wv = t >> 6;
    int i0 = b * CHUNK + t;       // element t of chunk
    int i1 = i0 + 256;            // element 256+t of chunk
    int v0 = (i0 < NNODE) ? counts[i0] : 0;
    int v1 = (i1 < NNODE) ? counts[i1] : 0;
    int x0 = v0, x1 = v1;
#pragma unroll
    for (int o = 1; o < 64; o <<= 1) { int y = __shfl_up(x0, o); if (lane >= o) x0 += y; }
#pragma unroll
    for (int o = 1; o < 64; o <<= 1) { int y = __shfl_up(x1, o); if (lane >= o) x1 += y; }
    if (lane == 63) { wt0[wv] = x0; wt1[wv] = x1; }
    __syncthreads();
    int base = pbase[b];
    int acc0 = base;
    for (int j = 0; j < wv; ++j) acc0 += wt0[j];
    int excl0 = acc0 + x0 - v0;
    int acc1 = base + wt0[0] + wt0[1] + wt0[2] + wt0[3];
    for (int j = 0; j < wv; ++j) acc1 += wt1[j];
    int excl1 = acc1 + x1 - v1;
    if (i0 < NNODE) { offsets[i0] = excl0; cursor[i0] = excl0; }
    if (i1 < NNODE) { offsets[i1] = excl1; cursor[i1] = excl1; }
}

__global__ void scatter_kernel(const int* __restrict__ rows, const int* __restrict__ cols,
                               const float* __restrict__ conn,
                               int* __restrict__ cursor, uint2* __restrict__ edge_s) {
    int e = blockIdx.x * 256 + threadIdx.x;
    if (e < NEDGE) {
        int r = rows[e];
        int o = atomicAdd(&cursor[r], 1);
        edge_s[o] = make_uint2((unsigned)cols[e], __float_as_uint(conn[e]));
    }
}

// ---------------------------------------------------------------------------
// Per-receiver softmax + weighted aggregation. 2 rows per wave, p-loop
// unrolled x4 for memory-level parallelism; one dwordx2 gather per edge
// covers both batches. No max-subtraction (|score| <= ~40, fp32-safe).
// ---------------------------------------------------------------------------
__global__ __launch_bounds__(256)
void aggregate_kernel(const int* __restrict__ offsets,
                      const uint2* __restrict__ edge_s,
                      const float* __restrict__ ksum,
                      const uint2* __restrict__ values_pk,
                      unsigned short* __restrict__ agg_bf) {
    int wave = threadIdx.x >> 6, lane = threadIdx.x & 63;
    int wid = blockIdx.x * 4 + wave;
    for (int rr = 0; rr < 2; ++rr) {
        int i = wid * 2 + rr;
        if (i >= NNODE) break;
        int start = offsets[i], len = offsets[i + 1] - start;
        float acc00 = 0.f, acc01 = 0.f, acc10 = 0.f, acc11 = 0.f;
        if (len > 0) {
            if (len <= 64) {
                float ex0 = 0.f, ex1 = 0.f; int colv = 0;
                if (lane < len) {
                    uint2 e = edge_s[start + lane];
                    colv = (int)e.x;
                    float cv = __uint_as_float(e.y);
                    ex0 = __expf(cv * ksum[colv]);
                    ex1 = __expf(cv * ksum[NNODE + colv]);
                }
                float s0 = ex0, s1 = ex1;
#pragma unroll
                for (int o = 1; o < 64; o <<= 1) { s0 += __shfl_xor(s0, o); s1 += __shfl_xor(s1, o); }
                float inv0 = 1.0f / s0, inv1 = 1.0f / s1;
                int p = 0;
                for (; p + 3 < len; p += 4) {
                    int c0 = __shfl(colv, p),     c1 = __shfl(colv, p + 1);
                    int c2 = __shfl(colv, p + 2), c3 = __shfl(colv, p + 3);
                    float wa0 = __shfl(ex0, p) * inv0,     wb0 = __shfl(ex1, p) * inv1;
                    float wa1 = __shfl(ex0, p + 1) * inv0, wb1 = __shfl(ex1, p + 1) * inv1;
                    float wa2 = __shfl(ex0, p + 2) * inv0, wb2 = __shfl(ex1, p + 2) * inv1;
                    float wa3 = __shfl(ex0, p + 3) * inv0, wb3 = __shfl(ex1, p + 3) * inv1;
                    uint2 v0 = values_pk[(size_t)c0 * 64 + lane];
                    uint2 v1 = values_pk[(size_t)c1 * 64 + lane];
                    uint2 v2 = values_pk[(size_t)c2 * 64 + lane];
                    uint2 v3 = values_pk[(size_t)c3 * 64 + lane];
                    acc00 += wa0 * __uint_as_float(v0.x << 16) + wa1 * __uint_as_float(v1.x << 16)
                           + wa2 * __uint_as_float(v2.x << 16) + wa3 * __uint_as_float(v3.x << 16);
                    acc01 += wa0 * __uint_as_float(v0.x & 0xFFFF0000u) + wa1 * __uint_as_float(v1.x & 0xFFFF0000u)
                           + wa2 * __uint_as_float(v2.x & 0xFFFF0000u) + wa3 * __uint_as_float(v3.x & 0xFFFF0000u);
                    acc10 += wb0 * __uint_as_float(v0.y << 16) + wb1 * __uint_as_float(v1.y << 16)
                           + wb2 * __uint_as_float(v2.y << 16) + wb3 * __uint_as_float(v3.y << 16);
                    acc11 += wb0 * __uint_as_float(v0.y & 0xFFFF0000u) + wb1 * __uint_as_float(v1.y & 0xFFFF0000u)
                           + wb2 * __uint_as_float(v2.y & 0xFFFF0000u) + wb3 * __uint_as_float(v3.y & 0xFFFF0000u);
                }
                for (; p < len; ++p) {
                    int c = __shfl(colv, p);
                    float w0 = __shfl(ex0, p) * inv0;
                    float w1 = __shfl(ex1, p) * inv1;
                    uint2 v = values_pk[(size_t)c * 64 + lane];
                    acc00 += w0 * __uint_as_float(v.x << 16);
                    acc01 += w0 * __uint_as_float(v.x & 0xFFFF0000u);
                    acc10 += w1 * __uint_as_float(v.y << 16);
                    acc11 += w1 * __uint_as_float(v.y & 0xFFFF0000u);
                }
            } else {
                float s0 = 0.f, s1 = 0.f;
                for (int basep = 0; basep < len; basep += 64) {
                    int q = basep + lane;
                    if (q < len) {
                        uint2 e = edge_s[start + q];
                        int c = (int)e.x;
                        float cv = __uint_as_float(e.y);
                        s0 += __expf(cv * ksum[c]);
                        s1 += __expf(cv * ksum[NNODE + c]);
                    }
                }
#pragma unroll
                for (int o = 1; o < 64; o <<= 1) { s0 += __shfl_xor(s0, o); s1 += __shfl_xor(s1, o); }
                float inv0 = 1.0f / s0, inv1 = 1.0f / s1;
                for (int p = 0; p < len; ++p) {
                    uint2 e = edge_s[start + p];
                    int c = (int)e.x;
                    float cv = __uint_as_float(e.y);
                    float w0 = __expf(cv * ksum[c]) * inv0;
                    float w1 = __expf(cv * ksum[NNODE + c]) * inv1;
                    uint2 v = values_pk[(size_t)c * 64 + lane];
                    acc00 += w0 * __uint_as_float(v.x << 16);
                    acc01 += w0 * __uint_as_float(v.x & 0xFFFF0000u);
                    acc10 += w1 * __uint_as_float(v.y << 16);
                    acc11 += w1 * __uint_as_float(v.y & 0xFFFF0000u);
                }
            }
        }
        unsigned o0 = ((unsigned)f2bf(acc01) << 16) | (unsigned)f2bf(acc00);
        unsigned o1 = ((unsigned)f2bf(acc11) << 16) | (unsigned)f2bf(acc10);
        ((unsigned*)(agg_bf + (size_t)i * VALD))[lane] = o0;
        ((unsigned*)(agg_bf + (size_t)(NNODE + i) * VALD))[lane] = o1;
    }
}

// ---------------------------------------------------------------------------
// out = LN(silu(agg @ out_w + out_b)) * g + b. 16 rows x 128 cols per block.
// ---------------------------------------------------------------------------
__global__ __launch_bounds__(256)
void out_kernel(const unsigned short* __restrict__ agg_bf,
                const unsigned short* __restrict__ owT,
                const float* __restrict__ ob,
                const float* __restrict__ lng, const float* __restrict__ lnb,
                float* __restrict__ out) {
    __shared__ float hs[16][VALD + 2];
    __shared__ float ps[16][16];
    __shared__ float psq[16][16];
    __shared__ float mu_s[16], rs_s[16];
    int m0 = blockIdx.x * 16;
    int tid = threadIdx.x;
    int wave = tid >> 6, lane = tid & 63;
    int m = lane & 15, quad = lane >> 4;
    int n0 = wave * 32;
    f32x4 a0 = {0.f, 0.f, 0.f, 0.f}, a1 = {0.f, 0.f, 0.f, 0.f};
    const unsigned short* arow = agg_bf + (size_t)(m0 + m) * VALD;
#pragma unroll
    for (int kk = 0; kk < 4; ++kk) {
        int k0 = kk * 32 + quad * 8;
        bf16x8 af = *(const bf16x8*)(arow + k0);
        bf16x8 b0 = *(const bf16x8*)(owT + (size_t)(n0 + m) * VALD + k0);
        bf16x8 b1 = *(const bf16x8*)(owT + (size_t)(n0 + 16 + m) * VALD + k0);
        a0 = __builtin_amdgcn_mfma_f32_16x16x32_bf16(af, b0, a0, 0, 0, 0);
        a1 = __builtin_amdgcn_mfma_f32_16x16x32_bf16(af, b1, a1, 0, 0, 0);
    }
#pragma unroll
    for (int r = 0; r < 4; ++r) {
        int row = quad * 4 + r;
        {
            int col = n0 + m;
            float h = a0[r] + ob[col];
            hs[row][col] = h / (1.f + __expf(-h));
        }
        {
            int col = n0 + 16 + m;
            float h = a1[r] + ob[col];
            hs[row][col] = h / (1.f + __expf(-h));
        }
    }
    __syncthreads();
    {
        int row = tid >> 4, seg = tid & 15;
        float s = 0.f, q = 0.f;
#pragma unroll
        for (int j = 0; j < 8; ++j) {
            float v = hs[row][seg * 8 + j];
            s += v; q += v * v;
        }
        ps[row][seg] = s; psq[row][seg] = q;
    }
    __syncthreads();
    if (tid < 16) {
        float s = 0.f, q = 0.f;
#pragma unroll
        for (int j = 0; j < 16; ++j) { s += ps[tid][j]; q += psq[tid][j]; }
        float mu = s * (1.f / 128.f);
        float var = q * (1.f / 128.f) - mu * mu;
        mu_s[tid] = mu;
        rs_s[tid] = rsqrtf(var + 1e-5f);
    }
    __syncthreads();
#pragma unroll
    for (int j = 0; j < 8; ++j) {
        int e = tid + 256 * j;
        int row = e >> 7, col = e & 127;
        out[(size_t)(m0 + row) * VALD + col] =
            (hs[row][col] - mu_s[row]) * rs_s[row] * lng[col] + lnb[col];
    }
}

// ---------------------------------------------------------------------------
extern "C" void kernel_launch(void* const* d_in, const int* in_sizes, int n_in,
                              void* d_out, int out_size, void* d_ws, size_t ws_size,
                              hipStream_t stream) {
    (void)in_sizes; (void)n_in; (void)out_size; (void)ws_size;
    const float* x    = (const float*)d_in[0];
    const float* conn = (const float*)d_in[1];
    const float* kw   = (const float*)d_in[2];
    const float* kb   = (const float*)d_in[3];
    const float* vw   = (const float*)d_in[4];
    const float* vb   = (const float*)d_in[5];
    const float* ow   = (const float*)d_in[6];
    const float* ob   = (const float*)d_in[7];
    const float* lng  = (const float*)d_in[8];
    const float* lnb  = (const float*)d_in[9];
    const int* rows   = (const int*)d_in[10];
    const int* cols   = (const int*)d_in[11];
    float* out        = (float*)d_out;

    char* w = (char*)d_ws;
    auto alloc = [&](size_t bytes) {
        char* p = w;
        w += (bytes + 255) & ~(size_t)255;
        return p;
    };
    uint2* values_pk       = (uint2*)alloc((size_t)NNODE * 512);          // 25.6 MB
    unsigned short* agg_bf = (unsigned short*)alloc((size_t)MTOT * VALD * 2); // 25.6 MB
    float* ksum   = (float*)alloc((size_t)MTOT * 4);
    float* kwsum  = (float*)alloc(256 * 4);
    int*   counts = (int*)alloc((size_t)NNODE * 4);
    int*   cursor = (int*)alloc((size_t)NNODE * 4);
    int*   offsets = (int*)alloc((size_t)(NNODE + 1) * 4);
    int*   psum   = (int*)alloc((size_t)NCHUNK * 4);
    int*   pbase  = (int*)alloc((size_t)NCHUNK * 4);
    uint2* edge_s = (uint2*)alloc((size_t)NEDGE * 8);                     // 6.4 MB
    unsigned short* vwT = (unsigned short*)alloc((size_t)INPD * VALD * 2);
    unsigned short* owT = (unsigned short*)alloc((size_t)VALD * VALD * 2);

    prep_kernel<<<129 + 196, 256, 0, stream>>>(kw, kb, vw, ow, kwsum, vwT, owT, counts);
    values_build_kernel<<<VBLK + (NEDGE + 511) / 512, 512, 0, stream>>>(
        x, vb, kwsum, vwT, rows, values_pk, ksum, counts);
    scan1_kernel<<<NCHUNK, 256, 0, stream>>>(counts, psum);
    scan2_kernel<<<1, 128, 0, stream>>>(psum, pbase, offsets);
    scan3_kernel<<<NCHUNK, 256, 0, stream>>>(counts, pbase, offsets, cursor);
    scatter_kernel<<<(NEDGE + 255) / 256, 256, 0, stream>>>(rows, cols, conn, cursor, edge_s);
    aggregate_kernel<<<(NNODE + 7) / 8, 256, 0, stream>>>(offsets, edge_s, ksum, values_pk, agg_bf);
    out_kernel<<<MTOT / 16, 256, 0, stream>>>(agg_bf, owT, ob, lng, lnb, out);
}

// Round 4
// 325.864 us; speedup vs baseline: 1.5406x; 1.0700x over previous
//
#include <hip/hip_runtime.h>
#include <hip/hip_bf16.h>

// BatchedSemiAttention: B=2, N=50000, E=800000, INP=128, KEY=64, VAL=128
#define NB    2
#define NNODE 50000
#define NEDGE 800000
#define INPD  128
#define KEYD  64
#define VALD  128
#define MTOT  (NB * NNODE)   // 100000 flattened (b,n) rows
#define VBLK  3125           // NNODE/16 blocks for the values GEMM part
#define CHUNK 512
#define NCHUNK ((NNODE + CHUNK - 1) / CHUNK)   // 98

typedef __attribute__((ext_vector_type(8))) short bf16x8;
typedef __attribute__((ext_vector_type(4))) float f32x4;

__device__ __forceinline__ unsigned short f2bf(float f) {
    unsigned u = __float_as_uint(f);
    u += 0x7FFFu + ((u >> 16) & 1u);   // RNE
    return (unsigned short)(u >> 16);
}

// ---------------------------------------------------------------------------
// Prep: bf16 transposes of v_w / out_w into [n][k]; kwsum (col-sums of k_w,
// +kb sum at [128]); zero the CSR counts. All fused: one launch.
// ---------------------------------------------------------------------------
__global__ void prep_kernel(const float* __restrict__ kw, const float* __restrict__ kb,
                            const float* __restrict__ vw, const float* __restrict__ ow,
                            float* __restrict__ kwsum,
                            unsigned short* __restrict__ vwT, unsigned short* __restrict__ owT,
                            int* __restrict__ counts) {
    int bid = blockIdx.x, tid = threadIdx.x;
    if (bid < 64) {
        int idx = bid * 256 + tid;            // [0,16384)
        int n = idx >> 7, k = idx & 127;
        vwT[idx] = f2bf(vw[k * VALD + n]);
    } else if (bid < 128) {
        int idx = (bid - 64) * 256 + tid;
        int n = idx >> 7, k = idx & 127;
        owT[idx] = f2bf(ow[k * VALD + n]);
    } else if (bid == 128) {
        if (tid < INPD) {
            float s = 0.f;
            for (int j = 0; j < KEYD; ++j) s += kw[tid * KEYD + j];
            kwsum[tid] = s;
        }
        if (tid == 0) {
            float s = 0.f;
            for (int j = 0; j < KEYD; ++j) s += kb[j];
            kwsum[INPD] = s;                  // kbsum
        }
    } else {
        int idx = (bid - 129) * 256 + tid;
        if (idx < NNODE) counts[idx] = 0;
    }
}

// ---------------------------------------------------------------------------
// Fused values GEMM (both batches, 16 nodes/block) + ksum + edge histogram.
// All global traffic coalesced via LDS staging:
//   xs  [32][132] fp32  - x tile (rows 0-15 = batch0, 16-31 = batch1), +4 pad
//   pk  [16][256] u16   - packed output tile, flushed as uint4/thread
// values_pk layout per node: 64 x uint2 { b0 cols(2l,2l+1) bf16x2,
// b1 cols(2l,2l+1) bf16x2 } -> one dwordx2 per edge in aggregate.
// ---------------------------------------------------------------------------
__global__ __launch_bounds__(512)
void values_build_kernel(const float* __restrict__ x, const float* __restrict__ vb,
                         const float* __restrict__ kwsum,
                         const unsigned short* __restrict__ vwT,
                         const int* __restrict__ rows_e,
                         uint2* __restrict__ values_pk, float* __restrict__ ksum,
                         int* __restrict__ counts) {
    __shared__ float xs[32 * 132];            // 16896 B
    __shared__ unsigned short pk[16 * 256];   // 8192 B
    if (blockIdx.x >= VBLK) {
        // histogram part, overlapped with the GEMM blocks
        int e = (blockIdx.x - VBLK) * 512 + threadIdx.x;
        if (e < NEDGE) atomicAdd(&counts[rows_e[e]], 1);
        return;
    }
    int node0 = blockIdx.x * 16;
    int tid = threadIdx.x;
    // Coalesced x-tile load: one float4 per thread per batch (2 x 8 KB contiguous).
    {
        float4 v0 = ((const float4*)(x + (size_t)node0 * INPD))[tid];
        float4 v1 = ((const float4*)(x + (size_t)(NNODE + node0) * INPD))[tid];
        int row = tid >> 5;           // 0..15
        int col = (tid & 31) * 4;     // 0..124
        *(float4*)(xs + row * 132 + col) = v0;
        *(float4*)(xs + (16 + row) * 132 + col) = v1;
    }
    __syncthreads();

    int wave = tid >> 6, lane = tid & 63;
    int m = lane & 15, quad = lane >> 4;
    int n0 = wave * 16;
    f32x4 acc0 = {0.f, 0.f, 0.f, 0.f};   // batch 0
    f32x4 acc1 = {0.f, 0.f, 0.f, 0.f};   // batch 1
    float kpart = 0.f;
    const float* r0 = xs + m * 132;
    const float* r1 = xs + (16 + m) * 132;
#pragma unroll
    for (int kk = 0; kk < 4; ++kk) {
        int k0 = kk * 32 + quad * 8;
        float4 a0 = *(const float4*)(r0 + k0);
        float4 a1 = *(const float4*)(r0 + k0 + 4);
        float4 c0 = *(const float4*)(r1 + k0);
        float4 c1 = *(const float4*)(r1 + k0 + 4);
        bf16x8 bfrag = *(const bf16x8*)(vwT + (size_t)(n0 + m) * INPD + k0);
        union { bf16x8 v; unsigned short h[8]; } ua;
        ua.h[0] = f2bf(a0.x); ua.h[1] = f2bf(a0.y); ua.h[2] = f2bf(a0.z); ua.h[3] = f2bf(a0.w);
        ua.h[4] = f2bf(a1.x); ua.h[5] = f2bf(a1.y); ua.h[6] = f2bf(a1.z); ua.h[7] = f2bf(a1.w);
        acc0 = __builtin_amdgcn_mfma_f32_16x16x32_bf16(ua.v, bfrag, acc0, 0, 0, 0);
        union { bf16x8 v; unsigned short h[8]; } ub;
        ub.h[0] = f2bf(c0.x); ub.h[1] = f2bf(c0.y); ub.h[2] = f2bf(c0.z); ub.h[3] = f2bf(c0.w);
        ub.h[4] = f2bf(c1.x); ub.h[5] = f2bf(c1.y); ub.h[6] = f2bf(c1.z); ub.h[7] = f2bf(c1.w);
        acc1 = __builtin_amdgcn_mfma_f32_16x16x32_bf16(ub.v, bfrag, acc1, 0, 0, 0);
        if (wave == 0) {
            float4 ka = *(const float4*)(kwsum + k0);
            float4 kc = *(const float4*)(kwsum + k0 + 4);
            kpart += a0.x * ka.x + a0.y * ka.y + a0.z * ka.z + a0.w * ka.w
                   + a1.x * kc.x + a1.y * kc.y + a1.z * kc.z + a1.w * kc.w;
        } else if (wave == 1) {
            float4 ka = *(const float4*)(kwsum + k0);
            float4 kc = *(const float4*)(kwsum + k0 + 4);
            kpart += c0.x * ka.x + c0.y * ka.y + c0.z * ka.z + c0.w * ka.w
                   + c1.x * kc.x + c1.y * kc.y + c1.z * kc.z + c1.w * kc.w;
        }
    }
    int col = n0 + m;
    float vbc = vb[col];
    int pairidx = (col >> 1) * 4 + (col & 1);   // ushort index within a node's 256
#pragma unroll
    for (int r = 0; r < 4; ++r) {
        int nl = quad * 4 + r;                  // node_local
        pk[nl * 256 + pairidx]     = f2bf(acc0[r] + vbc);   // batch 0
        pk[nl * 256 + pairidx + 2] = f2bf(acc1[r] + vbc);   // batch 1
    }
    if (wave < 2) {
        kpart += __shfl_xor(kpart, 16);
        kpart += __shfl_xor(kpart, 32);
        if (quad == 0) ksum[(wave == 0 ? 0 : NNODE) + node0 + m] = kpart + kwsum[INPD];
    }
    __syncthreads();
    // Coalesced flush: 512 threads x 16 B = 8 KB tile.
    {
        uint4 v = ((const uint4*)pk)[tid];
        ((uint4*)((char*)values_pk + (size_t)node0 * 512))[tid] = v;
    }
}

// ---------------------------------------------------------------------------
// Device-wide exclusive scan of counts -> offsets (+cursor copy), 3 phases.
// ---------------------------------------------------------------------------
__global__ __launch_bounds__(256)
void scan1_kernel(const int* __restrict__ counts, int* __restrict__ psum) {
    __shared__ int wsum[4];
    int b = blockIdx.x, t = threadIdx.x;
    int i0 = b * CHUNK + t, i1 = i0 + 256;
    int v = 0;
    if (i0 < NNODE) v += counts[i0];
    if (i1 < NNODE) v += counts[i1];
#pragma unroll
    for (int o = 1; o < 64; o <<= 1) v += __shfl_xor(v, o);
    int lane = t & 63, wv = t >> 6;
    if (lane == 0) wsum[wv] = v;
    __syncthreads();
    if (t == 0) psum[b] = wsum[0] + wsum[1] + wsum[2] + wsum[3];
}

__global__ __launch_bounds__(128)
void scan2_kernel(const int* __restrict__ psum, int* __restrict__ pbase,
                  int* __restrict__ offsets) {
    __shared__ int s[128];
    int t = threadIdx.x;
    int v = (t < NCHUNK) ? psum[t] : 0;
    s[t] = v;
    __syncthreads();
    for (int o = 1; o < 128; o <<= 1) {
        int y = (t >= o) ? s[t - o] : 0;
        __syncthreads();
        s[t] += y;
        __syncthreads();
    }
    if (t < NCHUNK) pbase[t] = s[t] - v;          // exclusive chunk base
    if (t == NCHUNK - 1) offsets[NNODE] = s[t];   // total edge count
}

__global__ __launch_bounds__(256)
void scan3_kernel(const int* __restrict__ counts, const int* __restrict__ pbase,
                  int* __restrict__ offsets, int* __restrict__ cursor) {
    __shared__ int wt0[4], wt1[4];
    int b = blockIdx.x, t = threadIdx.x;
    int lane = t & 63, wv = t >> 6;
    int i0 = b * CHUNK + t;       // element t of chunk
    int i1 = i0 + 256;            // element 256+t of chunk
    int v0 = (i0 < NNODE) ? counts[i0] : 0;
    int v1 = (i1 < NNODE) ? counts[i1] : 0;
    int x0 = v0, x1 = v1;
#pragma unroll
    for (int o = 1; o < 64; o <<= 1) { int y = __shfl_up(x0, o); if (lane >= o) x0 += y; }
#pragma unroll
    for (int o = 1; o < 64; o <<= 1) { int y = __shfl_up(x1, o); if (lane >= o) x1 += y; }
    if (lane == 63) { wt0[wv] = x0; wt1[wv] = x1; }
    __syncthreads();
    int base = pbase[b];
    int acc0 = base;
    for (int j = 0; j < wv; ++j) acc0 += wt0[j];
    int excl0 = acc0 + x0 - v0;
    int acc1 = base + wt0[0] + wt0[1] + wt0[2] + wt0[3];
    for (int j = 0; j < wv; ++j) acc1 += wt1[j];
    int excl1 = acc1 + x1 - v1;
    if (i0 < NNODE) { offsets[i0] = excl0; cursor[i0] = excl0; }
    if (i1 < NNODE) { offsets[i1] = excl1; cursor[i1] = excl1; }
}

__global__ void scatter_kernel(const int* __restrict__ rows, const int* __restrict__ cols,
                               const float* __restrict__ conn,
                               int* __restrict__ cursor, uint2* __restrict__ edge_s) {
    int e = blockIdx.x * 256 + threadIdx.x;
    if (e < NEDGE) {
        int r = rows[e];
        int o = atomicAdd(&cursor[r], 1);
        edge_s[o] = make_uint2((unsigned)cols[e], __float_as_uint(conn[e]));
    }
}

// ---------------------------------------------------------------------------
// Per-receiver softmax + weighted aggregation. 2 rows per wave, p-loop
// unrolled x4 for memory-level parallelism; one dwordx2 gather per edge
// covers both batches. No max-subtraction (|score| <= ~40, fp32-safe).
// ---------------------------------------------------------------------------
__global__ __launch_bounds__(256)
void aggregate_kernel(const int* __restrict__ offsets,
                      const uint2* __restrict__ edge_s,
                      const float* __restrict__ ksum,
                      const uint2* __restrict__ values_pk,
                      unsigned short* __restrict__ agg_bf) {
    int wave = threadIdx.x >> 6, lane = threadIdx.x & 63;
    int wid = blockIdx.x * 4 + wave;
    for (int rr = 0; rr < 2; ++rr) {
        int i = wid * 2 + rr;
        if (i >= NNODE) break;
        int start = offsets[i], len = offsets[i + 1] - start;
        float acc00 = 0.f, acc01 = 0.f, acc10 = 0.f, acc11 = 0.f;
        if (len > 0) {
            if (len <= 64) {
                float ex0 = 0.f, ex1 = 0.f; int colv = 0;
                if (lane < len) {
                    uint2 e = edge_s[start + lane];
                    colv = (int)e.x;
                    float cv = __uint_as_float(e.y);
                    ex0 = __expf(cv * ksum[colv]);
                    ex1 = __expf(cv * ksum[NNODE + colv]);
                }
                float s0 = ex0, s1 = ex1;
#pragma unroll
                for (int o = 1; o < 64; o <<= 1) { s0 += __shfl_xor(s0, o); s1 += __shfl_xor(s1, o); }
                float inv0 = 1.0f / s0, inv1 = 1.0f / s1;
                int p = 0;
                for (; p + 3 < len; p += 4) {
                    int c0 = __shfl(colv, p),     c1 = __shfl(colv, p + 1);
                    int c2 = __shfl(colv, p + 2), c3 = __shfl(colv, p + 3);
                    float wa0 = __shfl(ex0, p) * inv0,     wb0 = __shfl(ex1, p) * inv1;
                    float wa1 = __shfl(ex0, p + 1) * inv0, wb1 = __shfl(ex1, p + 1) * inv1;
                    float wa2 = __shfl(ex0, p + 2) * inv0, wb2 = __shfl(ex1, p + 2) * inv1;
                    float wa3 = __shfl(ex0, p + 3) * inv0, wb3 = __shfl(ex1, p + 3) * inv1;
                    uint2 v0 = values_pk[(size_t)c0 * 64 + lane];
                    uint2 v1 = values_pk[(size_t)c1 * 64 + lane];
                    uint2 v2 = values_pk[(size_t)c2 * 64 + lane];
                    uint2 v3 = values_pk[(size_t)c3 * 64 + lane];
                    acc00 += wa0 * __uint_as_float(v0.x << 16) + wa1 * __uint_as_float(v1.x << 16)
                           + wa2 * __uint_as_float(v2.x << 16) + wa3 * __uint_as_float(v3.x << 16);
                    acc01 += wa0 * __uint_as_float(v0.x & 0xFFFF0000u) + wa1 * __uint_as_float(v1.x & 0xFFFF0000u)
                           + wa2 * __uint_as_float(v2.x & 0xFFFF0000u) + wa3 * __uint_as_float(v3.x & 0xFFFF0000u);
                    acc10 += wb0 * __uint_as_float(v0.y << 16) + wb1 * __uint_as_float(v1.y << 16)
                           + wb2 * __uint_as_float(v2.y << 16) + wb3 * __uint_as_float(v3.y << 16);
                    acc11 += wb0 * __uint_as_float(v0.y & 0xFFFF0000u) + wb1 * __uint_as_float(v1.y & 0xFFFF0000u)
                           + wb2 * __uint_as_float(v2.y & 0xFFFF0000u) + wb3 * __uint_as_float(v3.y & 0xFFFF0000u);
                }
                for (; p < len; ++p) {
                    int c = __shfl(colv, p);
                    float w0 = __shfl(ex0, p) * inv0;
                    float w1 = __shfl(ex1, p) * inv1;
                    uint2 v = values_pk[(size_t)c * 64 + lane];
                    acc00 += w0 * __uint_as_float(v.x << 16);
                    acc01 += w0 * __uint_as_float(v.x & 0xFFFF0000u);
                    acc10 += w1 * __uint_as_float(v.y << 16);
                    acc11 += w1 * __uint_as_float(v.y & 0xFFFF0000u);
                }
            } else {
                float s0 = 0.f, s1 = 0.f;
                for (int basep = 0; basep < len; basep += 64) {
                    int q = basep + lane;
                    if (q < len) {
                        uint2 e = edge_s[start + q];
                        int c = (int)e.x;
                        float cv = __uint_as_float(e.y);
                        s0 += __expf(cv * ksum[c]);
                        s1 += __expf(cv * ksum[NNODE + c]);
                    }
                }
#pragma unroll
                for (int o = 1; o < 64; o <<= 1) { s0 += __shfl_xor(s0, o); s1 += __shfl_xor(s1, o); }
                float inv0 = 1.0f / s0, inv1 = 1.0f / s1;
                for (int p = 0; p < len; ++p) {
                    uint2 e = edge_s[start + p];
                    int c = (int)e.x;
                    float cv = __uint_as_float(e.y);
                    float w0 = __expf(cv * ksum[c]) * inv0;
                    float w1 = __expf(cv * ksum[NNODE + c]) * inv1;
                    uint2 v = values_pk[(size_t)c * 64 + lane];
                    acc00 += w0 * __uint_as_float(v.x << 16);
                    acc01 += w0 * __uint_as_float(v.x & 0xFFFF0000u);
                    acc10 += w1 * __uint_as_float(v.y << 16);
                    acc11 += w1 * __uint_as_float(v.y & 0xFFFF0000u);
                }
            }
        }
        unsigned o0 = ((unsigned)f2bf(acc01) << 16) | (unsigned)f2bf(acc00);
        unsigned o1 = ((unsigned)f2bf(acc11) << 16) | (unsigned)f2bf(acc10);
        ((unsigned*)(agg_bf + (size_t)i * VALD))[lane] = o0;
        ((unsigned*)(agg_bf + (size_t)(NNODE + i) * VALD))[lane] = o1;
    }
}

// ---------------------------------------------------------------------------
// out = LN(silu(agg @ out_w + out_b)) * g + b. 16 rows x 128 cols per block.
// ---------------------------------------------------------------------------
__global__ __launch_bounds__(256)
void out_kernel(const unsigned short* __restrict__ agg_bf,
                const unsigned short* __restrict__ owT,
                const float* __restrict__ ob,
                const float* __restrict__ lng, const float* __restrict__ lnb,
                float* __restrict__ out) {
    __shared__ float hs[16][VALD + 2];
    __shared__ float ps[16][16];
    __shared__ float psq[16][16];
    __shared__ float mu_s[16], rs_s[16];
    int m0 = blockIdx.x * 16;
    int tid = threadIdx.x;
    int wave = tid >> 6, lane = tid & 63;
    int m = lane & 15, quad = lane >> 4;
    int n0 = wave * 32;
    f32x4 a0 = {0.f, 0.f, 0.f, 0.f}, a1 = {0.f, 0.f, 0.f, 0.f};
    const unsigned short* arow = agg_bf + (size_t)(m0 + m) * VALD;
#pragma unroll
    for (int kk = 0; kk < 4; ++kk) {
        int k0 = kk * 32 + quad * 8;
        bf16x8 af = *(const bf16x8*)(arow + k0);
        bf16x8 b0 = *(const bf16x8*)(owT + (size_t)(n0 + m) * VALD + k0);
        bf16x8 b1 = *(const bf16x8*)(owT + (size_t)(n0 + 16 + m) * VALD + k0);
        a0 = __builtin_amdgcn_mfma_f32_16x16x32_bf16(af, b0, a0, 0, 0, 0);
        a1 = __builtin_amdgcn_mfma_f32_16x16x32_bf16(af, b1, a1, 0, 0, 0);
    }
#pragma unroll
    for (int r = 0; r < 4; ++r) {
        int row = quad * 4 + r;
        {
            int col = n0 + m;
            float h = a0[r] + ob[col];
            hs[row][col] = h / (1.f + __expf(-h));
        }
        {
            int col = n0 + 16 + m;
            float h = a1[r] + ob[col];
            hs[row][col] = h / (1.f + __expf(-h));
        }
    }
    __syncthreads();
    {
        int row = tid >> 4, seg = tid & 15;
        float s = 0.f, q = 0.f;
#pragma unroll
        for (int j = 0; j < 8; ++j) {
            float v = hs[row][seg * 8 + j];
            s += v; q += v * v;
        }
        ps[row][seg] = s; psq[row][seg] = q;
    }
    __syncthreads();
    if (tid < 16) {
        float s = 0.f, q = 0.f;
#pragma unroll
        for (int j = 0; j < 16; ++j) { s += ps[tid][j]; q += psq[tid][j]; }
        float mu = s * (1.f / 128.f);
        float var = q * (1.f / 128.f) - mu * mu;
        mu_s[tid] = mu;
        rs_s[tid] = rsqrtf(var + 1e-5f);
    }
    __syncthreads();
#pragma unroll
    for (int j = 0; j < 8; ++j) {
        int e = tid + 256 * j;
        int row = e >> 7, col = e & 127;
        out[(size_t)(m0 + row) * VALD + col] =
            (hs[row][col] - mu_s[row]) * rs_s[row] * lng[col] + lnb[col];
    }
}

// ---------------------------------------------------------------------------
extern "C" void kernel_launch(void* const* d_in, const int* in_sizes, int n_in,
                              void* d_out, int out_size, void* d_ws, size_t ws_size,
                              hipStream_t stream) {
    (void)in_sizes; (void)n_in; (void)out_size; (void)ws_size;
    const float* x    = (const float*)d_in[0];
    const float* conn = (const float*)d_in[1];
    const float* kw   = (const float*)d_in[2];
    const float* kb   = (const float*)d_in[3];
    const float* vw   = (const float*)d_in[4];
    const float* vb   = (const float*)d_in[5];
    const float* ow   = (const float*)d_in[6];
    const float* ob   = (const float*)d_in[7];
    const float* lng  = (const float*)d_in[8];
    const float* lnb  = (const float*)d_in[9];
    const int* rows   = (const int*)d_in[10];
    const int* cols   = (const int*)d_in[11];
    float* out        = (float*)d_out;

    char* w = (char*)d_ws;
    auto alloc = [&](size_t bytes) {
        char* p = w;
        w += (bytes + 255) & ~(size_t)255;
        return p;
    };
    uint2* values_pk       = (uint2*)alloc((size_t)NNODE * 512);          // 25.6 MB
    unsigned short* agg_bf = (unsigned short*)alloc((size_t)MTOT * VALD * 2); // 25.6 MB
    float* ksum   = (float*)alloc((size_t)MTOT * 4);
    float* kwsum  = (float*)alloc(256 * 4);
    int*   counts = (int*)alloc((size_t)NNODE * 4);
    int*   cursor = (int*)alloc((size_t)NNODE * 4);
    int*   offsets = (int*)alloc((size_t)(NNODE + 1) * 4);
    int*   psum   = (int*)alloc((size_t)NCHUNK * 4);
    int*   pbase  = (int*)alloc((size_t)NCHUNK * 4);
    uint2* edge_s = (uint2*)alloc((size_t)NEDGE * 8);                     // 6.4 MB
    unsigned short* vwT = (unsigned short*)alloc((size_t)INPD * VALD * 2);
    unsigned short* owT = (unsigned short*)alloc((size_t)VALD * VALD * 2);

    prep_kernel<<<129 + 196, 256, 0, stream>>>(kw, kb, vw, ow, kwsum, vwT, owT, counts);
    values_build_kernel<<<VBLK + (NEDGE + 511) / 512, 512, 0, stream>>>(
        x, vb, kwsum, vwT, rows, values_pk, ksum, counts);
    scan1_kernel<<<NCHUNK, 256, 0, stream>>>(counts, psum);
    scan2_kernel<<<1, 128, 0, stream>>>(psum, pbase, offsets);
    scan3_kernel<<<NCHUNK, 256, 0, stream>>>(counts, pbase, offsets, cursor);
    scatter_kernel<<<(NEDGE + 255) / 256, 256, 0, stream>>>(rows, cols, conn, cursor, edge_s);
    aggregate_kernel<<<(NNODE + 7) / 8, 256, 0, stream>>>(offsets, edge_s, ksum, values_pk, agg_bf);
    out_kernel<<<MTOT / 16, 256, 0, stream>>>(agg_bf, owT, ob, lng, lnb, out);
}